// Round 13
// baseline (1827.595 us; speedup 1.0000x reference)
//
#include <hip/hip_runtime.h>
#include <math.h>

// Problem constants
#define BB 4
#define SS 1024
#define DD 768
#define HH 12
#define DHD 64
#define MROWS 4096
#define FF 3072

typedef unsigned short u16;
typedef float f32x4 __attribute__((ext_vector_type(4)));
typedef __bf16 bf16x8 __attribute__((ext_vector_type(8)));
typedef unsigned short u16x8 __attribute__((ext_vector_type(8)));
typedef unsigned short u16x4 __attribute__((ext_vector_type(4)));

static __device__ __forceinline__ float bf2f(u16 u) {
    union { unsigned int i; float f; } c; c.i = ((unsigned int)u) << 16; return c.f;
}
static __device__ __forceinline__ u16 f2bf(float f) {
    return __builtin_bit_cast(u16, static_cast<__bf16>(f));
}

// ---------------------------------------------------------------------------
// bf16 MFMA GEMM core. BM=64 x BN=128 tile, BK=32, 4 waves (2x2), each wave
// 32x64 = 2x4 MFMA frags. DEPTH-2 register prefetch (load tile k+2 while
// computing tile k) to cover global-load latency in low-occupancy launches.
//   A [M,Kstride] bf16 row-major (use cols [0,Klen)), Bt [N,Kstride] likewise.
// ---------------------------------------------------------------------------
#define LDST 40
static __device__ __forceinline__ void gemm64_core(
    const u16* __restrict__ A, const u16* __restrict__ Bt,
    int N, int Kstride, int Klen,
    const float* __restrict__ bias,
    const float* __restrict__ residf, const u16* __restrict__ residb,
    float* __restrict__ C, u16* __restrict__ Cbf, int ldcbf, int cboff,
    int do_gelu, int row0, int col0, u16* As, u16* Bs)
{
    const int tid  = threadIdx.x;
    const int lane = tid & 63;
    const int w    = tid >> 6;
    const int wm = (w >> 1) * 32;
    const int wn = (w & 1) * 64;

    const int arow = tid >> 2;
    const int akc  = (tid & 3) * 8;
    const int brow = tid >> 1;
    const int bkc  = (tid & 1) * 16;

    const u16* Ap = A  + (size_t)(row0 + arow) * Kstride + akc;
    const u16* Bp = Bt + (size_t)(col0 + brow) * Kstride + bkc;
    u16* AsW = &As[arow * LDST + akc];
    u16* BsW = &Bs[brow * LDST + bkc];

    const int fr = lane & 15;
    const int fk = (lane >> 4) * 8;

    f32x4 acc[2][4] = {};

    // depth-2 register pipeline
    u16x8 ar[2], br0[2], br1[2];
    ar[0]  = *(const u16x8*)(Ap);
    br0[0] = *(const u16x8*)(Bp);
    br1[0] = *(const u16x8*)(Bp + 8);
    if (Klen > 32) {
        ar[1]  = *(const u16x8*)(Ap + 32);
        br0[1] = *(const u16x8*)(Bp + 32);
        br1[1] = *(const u16x8*)(Bp + 40);
    }

    int cur = 0;
    for (int k0 = 0; k0 < Klen; k0 += 32) {
        if (k0) __syncthreads();
        *(u16x8*)AsW       = ar[cur];
        *(u16x8*)BsW       = br0[cur];
        *(u16x8*)(BsW + 8) = br1[cur];
        __syncthreads();

        if (k0 + 64 < Klen) {               // load 2 tiles ahead into slot cur
            ar[cur]  = *(const u16x8*)(Ap + k0 + 64);
            br0[cur] = *(const u16x8*)(Bp + k0 + 64);
            br1[cur] = *(const u16x8*)(Bp + k0 + 72);
        }

        bf16x8 af[2], bfv[4];
#pragma unroll
        for (int mi = 0; mi < 2; ++mi)
            af[mi] = __builtin_bit_cast(bf16x8,
                *(const u16x8*)(&As[(wm + 16 * mi + fr) * LDST + fk]));
#pragma unroll
        for (int ni = 0; ni < 4; ++ni)
            bfv[ni] = __builtin_bit_cast(bf16x8,
                *(const u16x8*)(&Bs[(wn + 16 * ni + fr) * LDST + fk]));
#pragma unroll
        for (int mi = 0; mi < 2; ++mi)
#pragma unroll
            for (int ni = 0; ni < 4; ++ni)
                acc[mi][ni] = __builtin_amdgcn_mfma_f32_16x16x32_bf16(
                    af[mi], bfv[ni], acc[mi][ni], 0, 0, 0);
        cur ^= 1;
    }

    const int orow0 = row0 + wm + (lane >> 4) * 4;
    const int ocol0 = col0 + wn + fr;
#pragma unroll
    for (int mi = 0; mi < 2; ++mi) {
#pragma unroll
        for (int ni = 0; ni < 4; ++ni) {
            const int col = ocol0 + ni * 16;
            const float bv = bias ? bias[col] : 0.0f;
#pragma unroll
            for (int r = 0; r < 4; ++r) {
                const int row = orow0 + mi * 16 + r;
                float v = acc[mi][ni][r] + bv;
                if (do_gelu) v = 0.5f * v * (1.0f + erff(v * 0.70710678118654752f));
                if (residf) v += residf[(size_t)row * N + col];
                if (residb) v += bf2f(residb[(size_t)row * N + col]);
                if (C)   C[(size_t)row * N + col] = v;
                if (Cbf) Cbf[(size_t)row * ldcbf + cboff + col] = f2bf(v);
            }
        }
    }
}

__global__ __launch_bounds__(256) void gemm64(
    const u16* __restrict__ A, const u16* __restrict__ Bt, int N, int K,
    const float* __restrict__ bias,
    const float* __restrict__ residf, const u16* __restrict__ residb,
    float* __restrict__ C, u16* __restrict__ Cbf, int ldcbf, int do_gelu)
{
    __shared__ u16 As[64 * LDST];
    __shared__ u16 Bs[128 * LDST];
    gemm64_core(A, Bt, N, K, K, bias, residf, residb, C, Cbf, ldcbf, 0, do_gelu,
                blockIdx.y * 64, blockIdx.x * 128, As, Bs);
}

// Split-K GEMM (gridDim.z = 2): z processes K-cols [z*Klen, (z+1)*Klen),
// writes raw fp32 partial to Cpair + z*MROWS*N (no bias/gelu/resid).
__global__ __launch_bounds__(256) void gemm64_sk(
    const u16* __restrict__ A, const u16* __restrict__ Bt, int N, int Kstride,
    int Klen, float* __restrict__ Cpair)
{
    __shared__ u16 As[64 * LDST];
    __shared__ u16 Bs[128 * LDST];
    const int z = blockIdx.z;
    const int koff = z * Klen;
    gemm64_core(A + koff, Bt + koff, N, Kstride, Klen,
                nullptr, nullptr, nullptr,
                Cpair + (size_t)z * MROWS * N, nullptr, 0, 0, 0,
                blockIdx.y * 64, blockIdx.x * 128, As, Bs);
}

__global__ __launch_bounds__(256) void gemm64_qkv3(
    const u16* __restrict__ A0, const u16* __restrict__ A1, const u16* __restrict__ A2,
    const u16* __restrict__ B0, const u16* __restrict__ B1, const u16* __restrict__ B2,
    u16* __restrict__ Cbf, int ldcbf)
{
    __shared__ u16 As[64 * LDST];
    __shared__ u16 Bs[128 * LDST];
    const int z = blockIdx.z;
    const u16* A = (z == 0) ? A0 : (z == 1) ? A1 : A2;
    const u16* B = (z == 0) ? B0 : (z == 1) ? B1 : B2;
    gemm64_core(A, B, DD, DD, DD, nullptr, nullptr, nullptr, nullptr, Cbf, ldcbf,
                z * DD, 0, blockIdx.y * 64, blockIdx.x * 128, As, Bs);
}

// ---------------------------------------------------------------------------
// Transpose + fp32->bf16
// ---------------------------------------------------------------------------
__global__ __launch_bounds__(256) void tcvt_kernel(
    const float* __restrict__ in, u16* __restrict__ out, int K, int N)
{
    __shared__ float t[32][33];
    const float* ib = in + (size_t)blockIdx.z * K * N;
    u16* ob = out + (size_t)blockIdx.z * K * N;
    const int n0 = blockIdx.x * 32, k0 = blockIdx.y * 32;
    const int tx = threadIdx.x & 31, ty = threadIdx.x >> 5;
#pragma unroll
    for (int j = 0; j < 4; ++j)
        t[ty + j * 8][tx] = ib[(size_t)(k0 + ty + j * 8) * N + n0 + tx];
    __syncthreads();
#pragma unroll
    for (int j = 0; j < 4; ++j)
        ob[(size_t)(n0 + ty + j * 8) * K + k0 + tx] = f2bf(t[tx][ty + j * 8]);
}

__global__ __launch_bounds__(256) void tcvt6_kernel(
    const float* __restrict__ w0, const float* __restrict__ w1,
    const float* __restrict__ w2, const float* __restrict__ w3,
    const float* __restrict__ w4, const float* __restrict__ w5,
    u16* __restrict__ Wm6)
{
    __shared__ float t[32][33];
    const int z = blockIdx.z;
    const int wi = z / 12, head = z % 12;
    const float* wsel = (wi == 0) ? w0 : (wi == 1) ? w1 : (wi == 2) ? w2 :
                        (wi == 3) ? w3 : (wi == 4) ? w4 : w5;
    const float* ib = wsel + (size_t)head * DD * DHD;
    u16* ob = Wm6 + (size_t)wi * DD * DD + (size_t)head * DHD * DD;
    const int n0 = blockIdx.x * 32, k0 = blockIdx.y * 32;
    const int tx = threadIdx.x & 31, ty = threadIdx.x >> 5;
#pragma unroll
    for (int j = 0; j < 4; ++j)
        t[ty + j * 8][tx] = ib[(size_t)(k0 + ty + j * 8) * DHD + n0 + tx];
    __syncthreads();
#pragma unroll
    for (int j = 0; j < 4; ++j)
        ob[(size_t)(n0 + ty + j * 8) * DD + k0 + tx] = f2bf(t[tx][ty + j * 8]);
}

__global__ __launch_bounds__(256) void cvt3_kernel(
    const float* __restrict__ s0, const float* __restrict__ s1,
    const float* __restrict__ s2,
    u16* __restrict__ d0, u16* __restrict__ d1, u16* __restrict__ d2, int n4)
{
    const int z = blockIdx.z;
    const float* s = (z == 0) ? s0 : (z == 1) ? s1 : s2;
    u16* d = (z == 0) ? d0 : (z == 1) ? d1 : d2;
    const int i = blockIdx.x * 256 + threadIdx.x;
    if (i < n4) {
        float4 v = ((const float4*)s)[i];
        ushort4 o;
        o.x = f2bf(v.x); o.y = f2bf(v.y); o.z = f2bf(v.z); o.w = f2bf(v.w);
        ((ushort4*)d)[i] = o;
    }
}

// ---------------------------------------------------------------------------
// MFMA flash attention, max-free exp2 softmax (validated R11).
// ---------------------------------------------------------------------------
#define AST 72
#define CSC 0.18033688011112042f   // 0.125 * log2(e)
__global__ __launch_bounds__(256) void attn_mfma_kernel(
    const u16* __restrict__ Q, const u16* __restrict__ K,
    const u16* __restrict__ V, int ldq, const int* __restrict__ kmask,
    u16* __restrict__ O, int causal)
{
    const int qt = causal ? ((int)gridDim.x - 1 - (int)blockIdx.x) : (int)blockIdx.x;
    const int bh = blockIdx.y;
    const int b  = bh / HH;
    const int h  = bh % HH;
    const int tid  = threadIdx.x;
    const int lane = tid & 63;
    const int w    = tid >> 6;
    const int lr = lane & 15;
    const int lg = lane >> 4;

    __shared__ u16 KPs[64 * AST];   // K tile; overwritten by P after QK^T
    __shared__ u16 Vt[64 * AST];

    const int row0 = qt * 64;
    const int q0w  = row0 + w * 16;

    bf16x8 qf[2];
    {
        const u16* qp = Q + (size_t)(b * SS + q0w + lr) * ldq + h * DHD + lg * 8;
        qf[0] = __builtin_bit_cast(bf16x8, *(const u16x8*)(qp));
        qf[1] = __builtin_bit_cast(bf16x8, *(const u16x8*)(qp + 32));
    }

    const int sr = tid >> 2;
    const int sc = (tid & 3) * 16;
    const int vkey = lane;
    const int vj = ((vkey & 15) << 2) | (vkey >> 4);   // permuted k-column
    const int dw = w * 16;

    f32x4 acc[4] = {};
    float lsum[4] = {0.0f, 0.0f, 0.0f, 0.0f};

    const int nkt = causal ? (qt + 1) : 16;

    u16x8 kr0, kr1, vr0, vr1;
    {
        const u16* kp = K + (size_t)(b * SS + sr) * ldq + h * DHD + sc;
        kr0 = *(const u16x8*)(kp);
        kr1 = *(const u16x8*)(kp + 8);
        const u16* vp = V + (size_t)(b * SS + vkey) * ldq + h * DHD + dw;
        vr0 = *(const u16x8*)(vp);
        vr1 = *(const u16x8*)(vp + 8);
    }

    for (int kt = 0; kt < nkt; ++kt) {
        const int kcol0 = kt * 64;
        if (kt) __syncthreads();        // all PV reads of KPs/Vt done

        *(u16x8*)(&KPs[sr * AST + sc])     = kr0;
        *(u16x8*)(&KPs[sr * AST + sc + 8]) = kr1;
#pragma unroll
        for (int j = 0; j < 8; ++j) Vt[(dw + j) * AST + vj] = vr0[j];
#pragma unroll
        for (int j = 0; j < 8; ++j) Vt[(dw + 8 + j) * AST + vj] = vr1[j];
        __syncthreads();

        if (kt + 1 < nkt) {
            const int kn = kcol0 + 64;
            const u16* kp = K + (size_t)(b * SS + kn + sr) * ldq + h * DHD + sc;
            kr0 = *(const u16x8*)(kp);
            kr1 = *(const u16x8*)(kp + 8);
            const u16* vp = V + (size_t)(b * SS + kn + vkey) * ldq + h * DHD + dw;
            vr0 = *(const u16x8*)(vp);
            vr1 = *(const u16x8*)(vp + 8);
        }

        // QK^T (consumes K tile)
        f32x4 s[4] = {};
#pragma unroll
        for (int fi = 0; fi < 4; ++fi) {
            bf16x8 kf0 = __builtin_bit_cast(bf16x8, *(const u16x8*)(&KPs[(fi * 16 + lr) * AST + lg * 8]));
            bf16x8 kf1 = __builtin_bit_cast(bf16x8, *(const u16x8*)(&KPs[(fi * 16 + lr) * AST + 32 + lg * 8]));
            s[fi] = __builtin_amdgcn_mfma_f32_16x16x32_bf16(qf[0], kf0, s[fi], 0, 0, 0);
            s[fi] = __builtin_amdgcn_mfma_f32_16x16x32_bf16(qf[1], kf1, s[fi], 0, 0, 0);
        }
        __syncthreads();   // K tile fully consumed; safe to overwrite with P

        float biasf[4];
#pragma unroll
        for (int fi = 0; fi < 4; ++fi)
            biasf[fi] = kmask[b * SS + kcol0 + fi * 16 + lr] ? 0.0f : -INFINITY;
        const bool diag = (causal != 0) && (kt == qt);

#pragma unroll
        for (int r = 0; r < 4; ++r) {
            const int qrow = q0w + lg * 4 + r;
            u16x4 pk;
            float rs = 0.0f;
#pragma unroll
            for (int fi = 0; fi < 4; ++fi) {
                float v = fmaf(s[fi][r], CSC, biasf[fi]);
                if (diag) {
                    const int key = kcol0 + fi * 16 + lr;
                    v = (key <= qrow) ? v : -INFINITY;
                }
                const float pv = exp2f(v);   // 0 for masked
                pk[fi] = f2bf(pv);
                rs += pv;
            }
            lsum[r] += rs;
            *(u16x4*)(&KPs[(w * 16 + lg * 4 + r) * AST + lr * 4]) = pk;
        }

        // PV: A = own strip of KPs (P), B = Vt; both k-permuted identically
#pragma unroll
        for (int kk = 0; kk < 2; ++kk) {
            bf16x8 pf = __builtin_bit_cast(bf16x8, *(const u16x8*)(&KPs[(w * 16 + lr) * AST + kk * 32 + lg * 8]));
#pragma unroll
            for (int di = 0; di < 4; ++di) {
                bf16x8 vf = __builtin_bit_cast(bf16x8, *(const u16x8*)(&Vt[(di * 16 + lr) * AST + kk * 32 + lg * 8]));
                acc[di] = __builtin_amdgcn_mfma_f32_16x16x32_bf16(pf, vf, acc[di], 0, 0, 0);
            }
        }
    }

    // one l-reduction for the whole kernel
#pragma unroll
    for (int r = 0; r < 4; ++r) {
        float l = lsum[r];
        l += __shfl_xor(l, 1);
        l += __shfl_xor(l, 2);
        l += __shfl_xor(l, 4);
        l += __shfl_xor(l, 8);
        const float inv = (l > 0.0f) ? (1.0f / l) : 0.0f;
        const size_t orow = (size_t)(b * SS + q0w + lg * 4 + r) * DD + h * DHD;
#pragma unroll
        for (int di = 0; di < 4; ++di)
            O[orow + di * 16 + lr] = f2bf(acc[di][r] * inv);
    }
}

// ---------------------------------------------------------------------------
// LayerNorm over last dim (768); nullable fp32 out / bf16 out.
// ---------------------------------------------------------------------------
__global__ __launch_bounds__(256) void ln_kernel(
    const float* __restrict__ X, const float* __restrict__ gma,
    const float* __restrict__ bta, float* __restrict__ Y, u16* __restrict__ Ybf)
{
    const int row = blockIdx.x;
    const int tid = threadIdx.x;
    const float* x = X + (size_t)row * DD;

    const float v0 = x[tid], v1 = x[tid + 256], v2 = x[tid + 512];

    __shared__ float sd[256];
    sd[tid] = v0 + v1 + v2;
    __syncthreads();
    for (int off = 128; off > 0; off >>= 1) {
        if (tid < off) sd[tid] += sd[tid + off];
        __syncthreads();
    }
    const float mean = sd[0] * (1.0f / 768.0f);
    __syncthreads();

    const float q0 = v0 - mean, q1 = v1 - mean, q2 = v2 - mean;
    sd[tid] = q0 * q0 + q1 * q1 + q2 * q2;
    __syncthreads();
    for (int off = 128; off > 0; off >>= 1) {
        if (tid < off) sd[tid] += sd[tid + off];
        __syncthreads();
    }
    const float var = sd[0] * (1.0f / 768.0f);
    const float inv = rsqrtf(var + 1e-5f);

    const float y0 = q0 * inv * gma[tid]       + bta[tid];
    const float y1 = q1 * inv * gma[tid + 256] + bta[tid + 256];
    const float y2 = q2 * inv * gma[tid + 512] + bta[tid + 512];
    if (Y) {
        float* y = Y + (size_t)row * DD;
        y[tid] = y0; y[tid + 256] = y1; y[tid + 512] = y2;
    }
    if (Ybf) {
        u16* yb = Ybf + (size_t)row * DD;
        yb[tid] = f2bf(y0); yb[tid + 256] = f2bf(y1); yb[tid + 512] = f2bf(y2);
    }
}

// ---------------------------------------------------------------------------
// LayerNorm over (C0 + C1 + bias + resid_bf16): split-K reduce fused in.
// ---------------------------------------------------------------------------
__global__ __launch_bounds__(256) void ln_red_kernel(
    const float* __restrict__ C0, const float* __restrict__ C1,
    const float* __restrict__ bias, const u16* __restrict__ resid,
    const float* __restrict__ gma, const float* __restrict__ bta,
    float* __restrict__ Y)
{
    const int row = blockIdx.x;
    const int tid = threadIdx.x;
    const size_t base = (size_t)row * DD;

    float v[3];
#pragma unroll
    for (int j = 0; j < 3; ++j) {
        const int i = tid + j * 256;
        v[j] = C0[base + i] + C1[base + i] + bias[i] + bf2f(resid[base + i]);
    }

    __shared__ float sd[256];
    sd[tid] = v[0] + v[1] + v[2];
    __syncthreads();
    for (int off = 128; off > 0; off >>= 1) {
        if (tid < off) sd[tid] += sd[tid + off];
        __syncthreads();
    }
    const float mean = sd[0] * (1.0f / 768.0f);
    __syncthreads();

    float q[3];
#pragma unroll
    for (int j = 0; j < 3; ++j) q[j] = v[j] - mean;
    sd[tid] = q[0] * q[0] + q[1] * q[1] + q[2] * q[2];
    __syncthreads();
    for (int off = 128; off > 0; off >>= 1) {
        if (tid < off) sd[tid] += sd[tid + off];
        __syncthreads();
    }
    const float var = sd[0] * (1.0f / 768.0f);
    const float inv = rsqrtf(var + 1e-5f);

    float* y = Y + base;
#pragma unroll
    for (int j = 0; j < 3; ++j) {
        const int i = tid + j * 256;
        y[i] = q[j] * inv * gma[i] + bta[i];
    }
}

// ---------------------------------------------------------------------------
extern "C" void kernel_launch(void* const* d_in, const int* in_sizes, int n_in,
                              void* d_out, int out_size, void* d_ws, size_t ws_size,
                              hipStream_t stream)
{
    (void)in_sizes; (void)n_in; (void)out_size; (void)ws_size;

    const float* key_enc   = (const float*)d_in[0];
    const float* value_enc = (const float*)d_in[1];
    const float* x         = (const float*)d_in[2];
    const int*   src_mask  = (const int*)d_in[3];
    const int*   tgt_mask  = (const int*)d_in[4];
    const float* Wq_m = (const float*)d_in[5];
    const float* Wk_m = (const float*)d_in[6];
    const float* Wv_m = (const float*)d_in[7];
    const float* Wo_m = (const float*)d_in[8];
    const float* Wq_c = (const float*)d_in[9];
    const float* Wk_c = (const float*)d_in[10];
    const float* Wv_c = (const float*)d_in[11];
    const float* Wo_c = (const float*)d_in[12];
    const float* ln1_g = (const float*)d_in[13];
    const float* ln1_b = (const float*)d_in[14];
    const float* ln2_g = (const float*)d_in[15];
    const float* ln2_b = (const float*)d_in[16];
    const float* ln3_g = (const float*)d_in[17];
    const float* ln3_b = (const float*)d_in[18];
    const float* W1 = (const float*)d_in[19];
    const float* b1 = (const float*)d_in[20];
    const float* W2 = (const float*)d_in[21];
    const float* b2 = (const float*)d_in[22];

    float* out = (float*)d_out;

    // workspace layout
    const size_t ACT = (size_t)MROWS * DD;
    const size_t WP  = (size_t)DD * DD;
    char* p = (char*)d_ws;
    u16* QKV  = (u16*)p;   p += 3 * ACT * 2;
    u16* BFx  = (u16*)p;   p += ACT * 2;
    u16* BFK  = (u16*)p;   p += ACT * 2;
    u16* BFV  = (u16*)p;   p += ACT * 2;
    u16* BF1a = (u16*)p;   p += ACT * 2;
    u16* BF1h = (u16*)p;   p += ACT * 2;
    float* T2 = (float*)p; p += ACT * 4;   // pre-LN fp32 / split-K partial 0
    float* T2b = (float*)p; p += ACT * 4;  // split-K partial 1
    u16* Wm6  = (u16*)p;   p += 6 * WP * 2;
    u16* Wom_t = (u16*)p;  p += WP * 2;
    u16* Woc_t = (u16*)p;  p += WP * 2;
    u16* W1t  = (u16*)p;   p += (size_t)DD * FF * 2;
    u16* W2t  = (u16*)p;   p += (size_t)DD * FF * 2;
    u16* MID  = QKV;   // [4096][3072] bf16 aliases QKV+BFx (dead by MLP)

    const dim3 blk(256);
    const int nc4 = (int)(ACT / 4);

    cvt3_kernel<<<dim3(nc4 / 256, 1, 3), blk, 0, stream>>>(
        x, key_enc, value_enc, BFx, BFK, BFV, nc4);
    tcvt6_kernel<<<dim3(2, 24, 72), blk, 0, stream>>>(
        Wq_m, Wk_m, Wv_m, Wq_c, Wk_c, Wv_c, Wm6);
    tcvt_kernel<<<dim3(24, 24, 1), blk, 0, stream>>>(Wo_m, Wom_t, DD, DD);
    tcvt_kernel<<<dim3(24, 24, 1), blk, 0, stream>>>(Wo_c, Woc_t, DD, DD);
    tcvt_kernel<<<dim3(96, 24, 1), blk, 0, stream>>>(W1, W1t, DD, FF);
    tcvt_kernel<<<dim3(24, 96, 1), blk, 0, stream>>>(W2, W2t, FF, DD);

    const dim3 gQKV(18, 64);
    const dim3 gP(6, 64);
    const dim3 gP3(6, 64, 3);
    const dim3 gM1(24, 64);
    const dim3 gM2(6, 64, 2);     // MLP2 split-K
    const dim3 gAttn(16, BB * HH);

    // Self-attention
    gemm64<<<gQKV, blk, 0, stream>>>(BFx, Wm6, 3 * DD, DD,
                                     nullptr, nullptr, nullptr,
                                     nullptr, QKV, 3 * DD, 0);
    attn_mfma_kernel<<<gAttn, blk, 0, stream>>>(QKV, QKV + DD, QKV + 2 * DD, 3 * DD,
                                                tgt_mask, BF1a, 1);
    gemm64<<<gP, blk, 0, stream>>>(BF1a, Wom_t, DD, DD,
                                   nullptr, x, nullptr,
                                   T2, nullptr, DD, 0);
    ln_kernel<<<MROWS, blk, 0, stream>>>(T2, ln1_g, ln1_b, nullptr, BF1h);

    // Cross-attention
    gemm64_qkv3<<<gP3, blk, 0, stream>>>(BF1h, BFK, BFV,
                                         Wm6 + 3 * WP, Wm6 + 4 * WP, Wm6 + 5 * WP,
                                         QKV, 3 * DD);
    attn_mfma_kernel<<<gAttn, blk, 0, stream>>>(QKV, QKV + DD, QKV + 2 * DD, 3 * DD,
                                                src_mask, BF1a, 0);
    gemm64<<<gP, blk, 0, stream>>>(BF1a, Woc_t, DD, DD,
                                   nullptr, nullptr, BF1h,
                                   T2, nullptr, DD, 0);
    ln_kernel<<<MROWS, blk, 0, stream>>>(T2, ln2_g, ln2_b, nullptr, BF1h);

    // MLP
    gemm64<<<gM1, blk, 0, stream>>>(BF1h, W1t, FF, DD,
                                    b1, nullptr, nullptr,
                                    nullptr, MID, FF, 1);
    gemm64_sk<<<gM2, blk, 0, stream>>>(MID, W2t, DD, FF, FF / 2, T2);
    ln_red_kernel<<<MROWS, blk, 0, stream>>>(T2, T2b, b2, BF1h,
                                             ln3_g, ln3_b, out);
}

// Round 14
// 350.578 us; speedup vs baseline: 5.2131x; 5.2131x over previous
//
#include <hip/hip_runtime.h>
#include <math.h>

// Problem constants
#define BB 4
#define SS 1024
#define DD 768
#define HH 12
#define DHD 64
#define MROWS 4096
#define FF 3072

typedef unsigned short u16;
typedef float f32x4 __attribute__((ext_vector_type(4)));
typedef __bf16 bf16x8 __attribute__((ext_vector_type(8)));
typedef unsigned short u16x8 __attribute__((ext_vector_type(8)));
typedef unsigned short u16x4 __attribute__((ext_vector_type(4)));

static __device__ __forceinline__ float bf2f(u16 u) {
    union { unsigned int i; float f; } c; c.i = ((unsigned int)u) << 16; return c.f;
}
static __device__ __forceinline__ u16 f2bf(float f) {
    return __builtin_bit_cast(u16, static_cast<__bf16>(f));
}

// ---------------------------------------------------------------------------
// bf16 MFMA GEMM core. BM=64 x BN=128 tile, BK=32, 4 waves (2x2), each wave
// 32x64 = 2x4 MFMA frags. Depth-2 prefetch via EXPLICIT 2-step unroll
// (all register indices compile-time static -- rule #20: no runtime-indexed
// ext_vector arrays). Klen must be a multiple of 64 (all K here are).
// ---------------------------------------------------------------------------
#define LDST 40
static __device__ __forceinline__ void gemm64_core(
    const u16* __restrict__ A, const u16* __restrict__ Bt,
    int N, int Kstride, int Klen,
    const float* __restrict__ bias,
    const float* __restrict__ residf, const u16* __restrict__ residb,
    float* __restrict__ C, u16* __restrict__ Cbf, int ldcbf, int cboff,
    int do_gelu, int row0, int col0, u16* As, u16* Bs)
{
    const int tid  = threadIdx.x;
    const int lane = tid & 63;
    const int w    = tid >> 6;
    const int wm = (w >> 1) * 32;
    const int wn = (w & 1) * 64;

    const int arow = tid >> 2;
    const int akc  = (tid & 3) * 8;
    const int brow = tid >> 1;
    const int bkc  = (tid & 1) * 16;

    const u16* Ap = A  + (size_t)(row0 + arow) * Kstride + akc;
    const u16* Bp = Bt + (size_t)(col0 + brow) * Kstride + bkc;
    u16* AsW = &As[arow * LDST + akc];
    u16* BsW = &Bs[brow * LDST + bkc];

    const int fr = lane & 15;
    const int fk = (lane >> 4) * 8;

    f32x4 acc[2][4] = {};

    // depth-2 pipeline, explicitly named slots (static indexing only)
    u16x8 a0, b00, b01, a1, b10, b11;
    a0  = *(const u16x8*)(Ap);
    b00 = *(const u16x8*)(Bp);
    b01 = *(const u16x8*)(Bp + 8);
    a1  = *(const u16x8*)(Ap + 32);
    b10 = *(const u16x8*)(Bp + 32);
    b11 = *(const u16x8*)(Bp + 40);

    for (int k0 = 0; k0 < Klen; k0 += 64) {
        // ---- step A: tile k0 ----
        if (k0) __syncthreads();
        *(u16x8*)AsW       = a0;
        *(u16x8*)BsW       = b00;
        *(u16x8*)(BsW + 8) = b01;
        __syncthreads();
        if (k0 + 64 < Klen) {
            a0  = *(const u16x8*)(Ap + k0 + 64);
            b00 = *(const u16x8*)(Bp + k0 + 64);
            b01 = *(const u16x8*)(Bp + k0 + 72);
        }
        {
            bf16x8 af[2], bfv[4];
#pragma unroll
            for (int mi = 0; mi < 2; ++mi)
                af[mi] = __builtin_bit_cast(bf16x8,
                    *(const u16x8*)(&As[(wm + 16 * mi + fr) * LDST + fk]));
#pragma unroll
            for (int ni = 0; ni < 4; ++ni)
                bfv[ni] = __builtin_bit_cast(bf16x8,
                    *(const u16x8*)(&Bs[(wn + 16 * ni + fr) * LDST + fk]));
#pragma unroll
            for (int mi = 0; mi < 2; ++mi)
#pragma unroll
                for (int ni = 0; ni < 4; ++ni)
                    acc[mi][ni] = __builtin_amdgcn_mfma_f32_16x16x32_bf16(
                        af[mi], bfv[ni], acc[mi][ni], 0, 0, 0);
        }

        // ---- step B: tile k0+32 ----
        __syncthreads();
        *(u16x8*)AsW       = a1;
        *(u16x8*)BsW       = b10;
        *(u16x8*)(BsW + 8) = b11;
        __syncthreads();
        if (k0 + 96 < Klen) {
            a1  = *(const u16x8*)(Ap + k0 + 96);
            b10 = *(const u16x8*)(Bp + k0 + 96);
            b11 = *(const u16x8*)(Bp + k0 + 104);
        }
        {
            bf16x8 af[2], bfv[4];
#pragma unroll
            for (int mi = 0; mi < 2; ++mi)
                af[mi] = __builtin_bit_cast(bf16x8,
                    *(const u16x8*)(&As[(wm + 16 * mi + fr) * LDST + fk]));
#pragma unroll
            for (int ni = 0; ni < 4; ++ni)
                bfv[ni] = __builtin_bit_cast(bf16x8,
                    *(const u16x8*)(&Bs[(wn + 16 * ni + fr) * LDST + fk]));
#pragma unroll
            for (int mi = 0; mi < 2; ++mi)
#pragma unroll
                for (int ni = 0; ni < 4; ++ni)
                    acc[mi][ni] = __builtin_amdgcn_mfma_f32_16x16x32_bf16(
                        af[mi], bfv[ni], acc[mi][ni], 0, 0, 0);
        }
    }

    const int orow0 = row0 + wm + (lane >> 4) * 4;
    const int ocol0 = col0 + wn + fr;
#pragma unroll
    for (int mi = 0; mi < 2; ++mi) {
#pragma unroll
        for (int ni = 0; ni < 4; ++ni) {
            const int col = ocol0 + ni * 16;
            const float bv = bias ? bias[col] : 0.0f;
#pragma unroll
            for (int r = 0; r < 4; ++r) {
                const int row = orow0 + mi * 16 + r;
                float v = acc[mi][ni][r] + bv;
                if (do_gelu) v = 0.5f * v * (1.0f + erff(v * 0.70710678118654752f));
                if (residf) v += residf[(size_t)row * N + col];
                if (residb) v += bf2f(residb[(size_t)row * N + col]);
                if (C)   C[(size_t)row * N + col] = v;
                if (Cbf) Cbf[(size_t)row * ldcbf + cboff + col] = f2bf(v);
            }
        }
    }
}

__global__ __launch_bounds__(256) void gemm64(
    const u16* __restrict__ A, const u16* __restrict__ Bt, int N, int K,
    const float* __restrict__ bias,
    const float* __restrict__ residf, const u16* __restrict__ residb,
    float* __restrict__ C, u16* __restrict__ Cbf, int ldcbf, int do_gelu)
{
    __shared__ u16 As[64 * LDST];
    __shared__ u16 Bs[128 * LDST];
    gemm64_core(A, Bt, N, K, K, bias, residf, residb, C, Cbf, ldcbf, 0, do_gelu,
                blockIdx.y * 64, blockIdx.x * 128, As, Bs);
}

// Split-K GEMM (gridDim.z = 2): z processes K-cols [z*Klen, (z+1)*Klen),
// writes raw fp32 partial to Cpair + z*MROWS*N (no bias/gelu/resid).
__global__ __launch_bounds__(256) void gemm64_sk(
    const u16* __restrict__ A, const u16* __restrict__ Bt, int N, int Kstride,
    int Klen, float* __restrict__ Cpair)
{
    __shared__ u16 As[64 * LDST];
    __shared__ u16 Bs[128 * LDST];
    const int z = blockIdx.z;
    const int koff = z * Klen;
    gemm64_core(A + koff, Bt + koff, N, Kstride, Klen,
                nullptr, nullptr, nullptr,
                Cpair + (size_t)z * MROWS * N, nullptr, 0, 0, 0,
                blockIdx.y * 64, blockIdx.x * 128, As, Bs);
}

__global__ __launch_bounds__(256) void gemm64_qkv3(
    const u16* __restrict__ A0, const u16* __restrict__ A1, const u16* __restrict__ A2,
    const u16* __restrict__ B0, const u16* __restrict__ B1, const u16* __restrict__ B2,
    u16* __restrict__ Cbf, int ldcbf)
{
    __shared__ u16 As[64 * LDST];
    __shared__ u16 Bs[128 * LDST];
    const int z = blockIdx.z;
    const u16* A = (z == 0) ? A0 : (z == 1) ? A1 : A2;
    const u16* B = (z == 0) ? B0 : (z == 1) ? B1 : B2;
    gemm64_core(A, B, DD, DD, DD, nullptr, nullptr, nullptr, nullptr, Cbf, ldcbf,
                z * DD, 0, blockIdx.y * 64, blockIdx.x * 128, As, Bs);
}

// ---------------------------------------------------------------------------
// Transpose + fp32->bf16
// ---------------------------------------------------------------------------
__global__ __launch_bounds__(256) void tcvt_kernel(
    const float* __restrict__ in, u16* __restrict__ out, int K, int N)
{
    __shared__ float t[32][33];
    const float* ib = in + (size_t)blockIdx.z * K * N;
    u16* ob = out + (size_t)blockIdx.z * K * N;
    const int n0 = blockIdx.x * 32, k0 = blockIdx.y * 32;
    const int tx = threadIdx.x & 31, ty = threadIdx.x >> 5;
#pragma unroll
    for (int j = 0; j < 4; ++j)
        t[ty + j * 8][tx] = ib[(size_t)(k0 + ty + j * 8) * N + n0 + tx];
    __syncthreads();
#pragma unroll
    for (int j = 0; j < 4; ++j)
        ob[(size_t)(n0 + ty + j * 8) * K + k0 + tx] = f2bf(t[tx][ty + j * 8]);
}

__global__ __launch_bounds__(256) void tcvt6_kernel(
    const float* __restrict__ w0, const float* __restrict__ w1,
    const float* __restrict__ w2, const float* __restrict__ w3,
    const float* __restrict__ w4, const float* __restrict__ w5,
    u16* __restrict__ Wm6)
{
    __shared__ float t[32][33];
    const int z = blockIdx.z;
    const int wi = z / 12, head = z % 12;
    const float* wsel = (wi == 0) ? w0 : (wi == 1) ? w1 : (wi == 2) ? w2 :
                        (wi == 3) ? w3 : (wi == 4) ? w4 : w5;
    const float* ib = wsel + (size_t)head * DD * DHD;
    u16* ob = Wm6 + (size_t)wi * DD * DD + (size_t)head * DHD * DD;
    const int n0 = blockIdx.x * 32, k0 = blockIdx.y * 32;
    const int tx = threadIdx.x & 31, ty = threadIdx.x >> 5;
#pragma unroll
    for (int j = 0; j < 4; ++j)
        t[ty + j * 8][tx] = ib[(size_t)(k0 + ty + j * 8) * DHD + n0 + tx];
    __syncthreads();
#pragma unroll
    for (int j = 0; j < 4; ++j)
        ob[(size_t)(n0 + ty + j * 8) * DD + k0 + tx] = f2bf(t[tx][ty + j * 8]);
}

__global__ __launch_bounds__(256) void cvt3_kernel(
    const float* __restrict__ s0, const float* __restrict__ s1,
    const float* __restrict__ s2,
    u16* __restrict__ d0, u16* __restrict__ d1, u16* __restrict__ d2, int n4)
{
    const int z = blockIdx.z;
    const float* s = (z == 0) ? s0 : (z == 1) ? s1 : s2;
    u16* d = (z == 0) ? d0 : (z == 1) ? d1 : d2;
    const int i = blockIdx.x * 256 + threadIdx.x;
    if (i < n4) {
        float4 v = ((const float4*)s)[i];
        ushort4 o;
        o.x = f2bf(v.x); o.y = f2bf(v.y); o.z = f2bf(v.z); o.w = f2bf(v.w);
        ((ushort4*)d)[i] = o;
    }
}

// ---------------------------------------------------------------------------
// MFMA flash attention, max-free exp2 softmax (validated R11).
// ---------------------------------------------------------------------------
#define AST 72
#define CSC 0.18033688011112042f   // 0.125 * log2(e)
__global__ __launch_bounds__(256) void attn_mfma_kernel(
    const u16* __restrict__ Q, const u16* __restrict__ K,
    const u16* __restrict__ V, int ldq, const int* __restrict__ kmask,
    u16* __restrict__ O, int causal)
{
    const int qt = causal ? ((int)gridDim.x - 1 - (int)blockIdx.x) : (int)blockIdx.x;
    const int bh = blockIdx.y;
    const int b  = bh / HH;
    const int h  = bh % HH;
    const int tid  = threadIdx.x;
    const int lane = tid & 63;
    const int w    = tid >> 6;
    const int lr = lane & 15;
    const int lg = lane >> 4;

    __shared__ u16 KPs[64 * AST];   // K tile; overwritten by P after QK^T
    __shared__ u16 Vt[64 * AST];

    const int row0 = qt * 64;
    const int q0w  = row0 + w * 16;

    bf16x8 qf[2];
    {
        const u16* qp = Q + (size_t)(b * SS + q0w + lr) * ldq + h * DHD + lg * 8;
        qf[0] = __builtin_bit_cast(bf16x8, *(const u16x8*)(qp));
        qf[1] = __builtin_bit_cast(bf16x8, *(const u16x8*)(qp + 32));
    }

    const int sr = tid >> 2;
    const int sc = (tid & 3) * 16;
    const int vkey = lane;
    const int vj = ((vkey & 15) << 2) | (vkey >> 4);   // permuted k-column
    const int dw = w * 16;

    f32x4 acc[4] = {};
    float lsum[4] = {0.0f, 0.0f, 0.0f, 0.0f};

    const int nkt = causal ? (qt + 1) : 16;

    u16x8 kr0, kr1, vr0, vr1;
    {
        const u16* kp = K + (size_t)(b * SS + sr) * ldq + h * DHD + sc;
        kr0 = *(const u16x8*)(kp);
        kr1 = *(const u16x8*)(kp + 8);
        const u16* vp = V + (size_t)(b * SS + vkey) * ldq + h * DHD + dw;
        vr0 = *(const u16x8*)(vp);
        vr1 = *(const u16x8*)(vp + 8);
    }

    for (int kt = 0; kt < nkt; ++kt) {
        const int kcol0 = kt * 64;
        if (kt) __syncthreads();        // all PV reads of KPs/Vt done

        *(u16x8*)(&KPs[sr * AST + sc])     = kr0;
        *(u16x8*)(&KPs[sr * AST + sc + 8]) = kr1;
#pragma unroll
        for (int j = 0; j < 8; ++j) Vt[(dw + j) * AST + vj] = vr0[j];
#pragma unroll
        for (int j = 0; j < 8; ++j) Vt[(dw + 8 + j) * AST + vj] = vr1[j];
        __syncthreads();

        if (kt + 1 < nkt) {
            const int kn = kcol0 + 64;
            const u16* kp = K + (size_t)(b * SS + kn + sr) * ldq + h * DHD + sc;
            kr0 = *(const u16x8*)(kp);
            kr1 = *(const u16x8*)(kp + 8);
            const u16* vp = V + (size_t)(b * SS + kn + vkey) * ldq + h * DHD + dw;
            vr0 = *(const u16x8*)(vp);
            vr1 = *(const u16x8*)(vp + 8);
        }

        // QK^T (consumes K tile)
        f32x4 s[4] = {};
#pragma unroll
        for (int fi = 0; fi < 4; ++fi) {
            bf16x8 kf0 = __builtin_bit_cast(bf16x8, *(const u16x8*)(&KPs[(fi * 16 + lr) * AST + lg * 8]));
            bf16x8 kf1 = __builtin_bit_cast(bf16x8, *(const u16x8*)(&KPs[(fi * 16 + lr) * AST + 32 + lg * 8]));
            s[fi] = __builtin_amdgcn_mfma_f32_16x16x32_bf16(qf[0], kf0, s[fi], 0, 0, 0);
            s[fi] = __builtin_amdgcn_mfma_f32_16x16x32_bf16(qf[1], kf1, s[fi], 0, 0, 0);
        }
        __syncthreads();   // K tile fully consumed; safe to overwrite with P

        float biasf[4];
#pragma unroll
        for (int fi = 0; fi < 4; ++fi)
            biasf[fi] = kmask[b * SS + kcol0 + fi * 16 + lr] ? 0.0f : -INFINITY;
        const bool diag = (causal != 0) && (kt == qt);

#pragma unroll
        for (int r = 0; r < 4; ++r) {
            const int qrow = q0w + lg * 4 + r;
            u16x4 pk;
            float rs = 0.0f;
#pragma unroll
            for (int fi = 0; fi < 4; ++fi) {
                float v = fmaf(s[fi][r], CSC, biasf[fi]);
                if (diag) {
                    const int key = kcol0 + fi * 16 + lr;
                    v = (key <= qrow) ? v : -INFINITY;
                }
                const float pv = exp2f(v);   // 0 for masked
                pk[fi] = f2bf(pv);
                rs += pv;
            }
            lsum[r] += rs;
            *(u16x4*)(&KPs[(w * 16 + lg * 4 + r) * AST + lr * 4]) = pk;
        }

        // PV: A = own strip of KPs (P), B = Vt; both k-permuted identically
#pragma unroll
        for (int kk = 0; kk < 2; ++kk) {
            bf16x8 pf = __builtin_bit_cast(bf16x8, *(const u16x8*)(&KPs[(w * 16 + lr) * AST + kk * 32 + lg * 8]));
#pragma unroll
            for (int di = 0; di < 4; ++di) {
                bf16x8 vf = __builtin_bit_cast(bf16x8, *(const u16x8*)(&Vt[(di * 16 + lr) * AST + kk * 32 + lg * 8]));
                acc[di] = __builtin_amdgcn_mfma_f32_16x16x32_bf16(pf, vf, acc[di], 0, 0, 0);
            }
        }
    }

    // one l-reduction for the whole kernel
#pragma unroll
    for (int r = 0; r < 4; ++r) {
        float l = lsum[r];
        l += __shfl_xor(l, 1);
        l += __shfl_xor(l, 2);
        l += __shfl_xor(l, 4);
        l += __shfl_xor(l, 8);
        const float inv = (l > 0.0f) ? (1.0f / l) : 0.0f;
        const size_t orow = (size_t)(b * SS + q0w + lg * 4 + r) * DD + h * DHD;
#pragma unroll
        for (int di = 0; di < 4; ++di)
            O[orow + di * 16 + lr] = f2bf(acc[di][r] * inv);
    }
}

// ---------------------------------------------------------------------------
// LayerNorm over last dim (768); nullable fp32 out / bf16 out.
// ---------------------------------------------------------------------------
__global__ __launch_bounds__(256) void ln_kernel(
    const float* __restrict__ X, const float* __restrict__ gma,
    const float* __restrict__ bta, float* __restrict__ Y, u16* __restrict__ Ybf)
{
    const int row = blockIdx.x;
    const int tid = threadIdx.x;
    const float* x = X + (size_t)row * DD;

    const float v0 = x[tid], v1 = x[tid + 256], v2 = x[tid + 512];

    __shared__ float sd[256];
    sd[tid] = v0 + v1 + v2;
    __syncthreads();
    for (int off = 128; off > 0; off >>= 1) {
        if (tid < off) sd[tid] += sd[tid + off];
        __syncthreads();
    }
    const float mean = sd[0] * (1.0f / 768.0f);
    __syncthreads();

    const float q0 = v0 - mean, q1 = v1 - mean, q2 = v2 - mean;
    sd[tid] = q0 * q0 + q1 * q1 + q2 * q2;
    __syncthreads();
    for (int off = 128; off > 0; off >>= 1) {
        if (tid < off) sd[tid] += sd[tid + off];
        __syncthreads();
    }
    const float var = sd[0] * (1.0f / 768.0f);
    const float inv = rsqrtf(var + 1e-5f);

    const float y0 = q0 * inv * gma[tid]       + bta[tid];
    const float y1 = q1 * inv * gma[tid + 256] + bta[tid + 256];
    const float y2 = q2 * inv * gma[tid + 512] + bta[tid + 512];
    if (Y) {
        float* y = Y + (size_t)row * DD;
        y[tid] = y0; y[tid + 256] = y1; y[tid + 512] = y2;
    }
    if (Ybf) {
        u16* yb = Ybf + (size_t)row * DD;
        yb[tid] = f2bf(y0); yb[tid + 256] = f2bf(y1); yb[tid + 512] = f2bf(y2);
    }
}

// ---------------------------------------------------------------------------
// LayerNorm over (C0 + C1 + bias + resid_bf16): split-K reduce fused in.
// ---------------------------------------------------------------------------
__global__ __launch_bounds__(256) void ln_red_kernel(
    const float* __restrict__ C0, const float* __restrict__ C1,
    const float* __restrict__ bias, const u16* __restrict__ resid,
    const float* __restrict__ gma, const float* __restrict__ bta,
    float* __restrict__ Y)
{
    const int row = blockIdx.x;
    const int tid = threadIdx.x;
    const size_t base = (size_t)row * DD;

    float v[3];
#pragma unroll
    for (int j = 0; j < 3; ++j) {
        const int i = tid + j * 256;
        v[j] = C0[base + i] + C1[base + i] + bias[i] + bf2f(resid[base + i]);
    }

    __shared__ float sd[256];
    sd[tid] = v[0] + v[1] + v[2];
    __syncthreads();
    for (int off = 128; off > 0; off >>= 1) {
        if (tid < off) sd[tid] += sd[tid + off];
        __syncthreads();
    }
    const float mean = sd[0] * (1.0f / 768.0f);
    __syncthreads();

    float q[3];
#pragma unroll
    for (int j = 0; j < 3; ++j) q[j] = v[j] - mean;
    sd[tid] = q[0] * q[0] + q[1] * q[1] + q[2] * q[2];
    __syncthreads();
    for (int off = 128; off > 0; off >>= 1) {
        if (tid < off) sd[tid] += sd[tid + off];
        __syncthreads();
    }
    const float var = sd[0] * (1.0f / 768.0f);
    const float inv = rsqrtf(var + 1e-5f);

    float* y = Y + base;
#pragma unroll
    for (int j = 0; j < 3; ++j) {
        const int i = tid + j * 256;
        y[i] = q[j] * inv * gma[i] + bta[i];
    }
}

// ---------------------------------------------------------------------------
extern "C" void kernel_launch(void* const* d_in, const int* in_sizes, int n_in,
                              void* d_out, int out_size, void* d_ws, size_t ws_size,
                              hipStream_t stream)
{
    (void)in_sizes; (void)n_in; (void)out_size; (void)ws_size;

    const float* key_enc   = (const float*)d_in[0];
    const float* value_enc = (const float*)d_in[1];
    const float* x         = (const float*)d_in[2];
    const int*   src_mask  = (const int*)d_in[3];
    const int*   tgt_mask  = (const int*)d_in[4];
    const float* Wq_m = (const float*)d_in[5];
    const float* Wk_m = (const float*)d_in[6];
    const float* Wv_m = (const float*)d_in[7];
    const float* Wo_m = (const float*)d_in[8];
    const float* Wq_c = (const float*)d_in[9];
    const float* Wk_c = (const float*)d_in[10];
    const float* Wv_c = (const float*)d_in[11];
    const float* Wo_c = (const float*)d_in[12];
    const float* ln1_g = (const float*)d_in[13];
    const float* ln1_b = (const float*)d_in[14];
    const float* ln2_g = (const float*)d_in[15];
    const float* ln2_b = (const float*)d_in[16];
    const float* ln3_g = (const float*)d_in[17];
    const float* ln3_b = (const float*)d_in[18];
    const float* W1 = (const float*)d_in[19];
    const float* b1 = (const float*)d_in[20];
    const float* W2 = (const float*)d_in[21];
    const float* b2 = (const float*)d_in[22];

    float* out = (float*)d_out;

    // workspace layout
    const size_t ACT = (size_t)MROWS * DD;
    const size_t WP  = (size_t)DD * DD;
    char* p = (char*)d_ws;
    u16* QKV  = (u16*)p;   p += 3 * ACT * 2;
    u16* BFx  = (u16*)p;   p += ACT * 2;
    u16* BFK  = (u16*)p;   p += ACT * 2;
    u16* BFV  = (u16*)p;   p += ACT * 2;
    u16* BF1a = (u16*)p;   p += ACT * 2;
    u16* BF1h = (u16*)p;   p += ACT * 2;
    float* T2 = (float*)p; p += ACT * 4;   // pre-LN fp32 / split-K partial 0
    float* T2b = (float*)p; p += ACT * 4;  // split-K partial 1
    u16* Wm6  = (u16*)p;   p += 6 * WP * 2;
    u16* Wom_t = (u16*)p;  p += WP * 2;
    u16* Woc_t = (u16*)p;  p += WP * 2;
    u16* W1t  = (u16*)p;   p += (size_t)DD * FF * 2;
    u16* W2t  = (u16*)p;   p += (size_t)DD * FF * 2;
    u16* MID  = QKV;   // [4096][3072] bf16 aliases QKV+BFx (dead by MLP)

    const dim3 blk(256);
    const int nc4 = (int)(ACT / 4);

    cvt3_kernel<<<dim3(nc4 / 256, 1, 3), blk, 0, stream>>>(
        x, key_enc, value_enc, BFx, BFK, BFV, nc4);
    tcvt6_kernel<<<dim3(2, 24, 72), blk, 0, stream>>>(
        Wq_m, Wk_m, Wv_m, Wq_c, Wk_c, Wv_c, Wm6);
    tcvt_kernel<<<dim3(24, 24, 1), blk, 0, stream>>>(Wo_m, Wom_t, DD, DD);
    tcvt_kernel<<<dim3(24, 24, 1), blk, 0, stream>>>(Wo_c, Woc_t, DD, DD);
    tcvt_kernel<<<dim3(96, 24, 1), blk, 0, stream>>>(W1, W1t, DD, FF);
    tcvt_kernel<<<dim3(24, 96, 1), blk, 0, stream>>>(W2, W2t, FF, DD);

    const dim3 gQKV(18, 64);
    const dim3 gP(6, 64);
    const dim3 gP3(6, 64, 3);
    const dim3 gM1(24, 64);
    const dim3 gM2(6, 64, 2);     // MLP2 split-K
    const dim3 gAttn(16, BB * HH);

    // Self-attention
    gemm64<<<gQKV, blk, 0, stream>>>(BFx, Wm6, 3 * DD, DD,
                                     nullptr, nullptr, nullptr,
                                     nullptr, QKV, 3 * DD, 0);
    attn_mfma_kernel<<<gAttn, blk, 0, stream>>>(QKV, QKV + DD, QKV + 2 * DD, 3 * DD,
                                                tgt_mask, BF1a, 1);
    gemm64<<<gP, blk, 0, stream>>>(BF1a, Wom_t, DD, DD,
                                   nullptr, x, nullptr,
                                   T2, nullptr, DD, 0);
    ln_kernel<<<MROWS, blk, 0, stream>>>(T2, ln1_g, ln1_b, nullptr, BF1h);

    // Cross-attention
    gemm64_qkv3<<<gP3, blk, 0, stream>>>(BF1h, BFK, BFV,
                                         Wm6 + 3 * WP, Wm6 + 4 * WP, Wm6 + 5 * WP,
                                         QKV, 3 * DD);
    attn_mfma_kernel<<<gAttn, blk, 0, stream>>>(QKV, QKV + DD, QKV + 2 * DD, 3 * DD,
                                                src_mask, BF1a, 0);
    gemm64<<<gP, blk, 0, stream>>>(BF1a, Woc_t, DD, DD,
                                   nullptr, nullptr, BF1h,
                                   T2, nullptr, DD, 0);
    ln_kernel<<<MROWS, blk, 0, stream>>>(T2, ln2_g, ln2_b, nullptr, BF1h);

    // MLP
    gemm64<<<gM1, blk, 0, stream>>>(BF1h, W1t, FF, DD,
                                    b1, nullptr, nullptr,
                                    nullptr, MID, FF, 1);
    gemm64_sk<<<gM2, blk, 0, stream>>>(MID, W2t, DD, FF, FF / 2, T2);
    ln_red_kernel<<<MROWS, blk, 0, stream>>>(T2, T2b, b2, BF1h,
                                             ln3_g, ln3_b, out);
}

// Round 15
// 337.033 us; speedup vs baseline: 5.4226x; 1.0402x over previous
//
#include <hip/hip_runtime.h>
#include <math.h>

// Problem constants
#define BB 4
#define SS 1024
#define DD 768
#define HH 12
#define DHD 64
#define MROWS 4096
#define FF 3072

typedef unsigned short u16;
typedef float f32x4 __attribute__((ext_vector_type(4)));
typedef __bf16 bf16x8 __attribute__((ext_vector_type(8)));
typedef unsigned short u16x8 __attribute__((ext_vector_type(8)));
typedef unsigned short u16x4 __attribute__((ext_vector_type(4)));

static __device__ __forceinline__ float bf2f(u16 u) {
    union { unsigned int i; float f; } c; c.i = ((unsigned int)u) << 16; return c.f;
}
static __device__ __forceinline__ u16 f2bf(float f) {
    return __builtin_bit_cast(u16, static_cast<__bf16>(f));
}

#define LDST 40

// ---------------------------------------------------------------------------
// 128x128-tile bf16 MFMA GEMM. 4 waves (2x2), each wave 64x64 = 4x4 frags,
// BK=32, 16 MFMA + 8 ds_read_b128 per K-step per wave. Depth-2 prefetch via
// explicit 2-step unroll (static register indices only). K % 64 == 0.
// ---------------------------------------------------------------------------
static __device__ __forceinline__ void gemm128_core(
    const u16* __restrict__ A, const u16* __restrict__ Bt,
    int K,
    const float* __restrict__ bias, int do_gelu,
    u16* __restrict__ Cbf, int ldcbf, int cboff,
    int row0, int col0, u16* As, u16* Bs)
{
    const int tid  = threadIdx.x;
    const int lane = tid & 63;
    const int w    = tid >> 6;
    const int wm = (w >> 1) * 64;
    const int wn = (w & 1) * 64;

    const int srow = tid >> 1;            // 0..127
    const int skc  = (tid & 1) * 16;      // elems 0 or 16 (two 8-elem chunks)

    const u16* Ap = A  + (size_t)(row0 + srow) * K + skc;
    const u16* Bp = Bt + (size_t)(col0 + srow) * K + skc;
    u16* AsW = &As[srow * LDST + skc];
    u16* BsW = &Bs[srow * LDST + skc];

    const int fr = lane & 15;
    const int fk = (lane >> 4) * 8;

    f32x4 acc[4][4] = {};

    // depth-2 pipeline, named slots
    u16x8 aa0, aa1, ba0, ba1;   // step-A tile
    u16x8 ab0, ab1, bb0, bb1;   // step-B tile
    aa0 = *(const u16x8*)(Ap);
    aa1 = *(const u16x8*)(Ap + 8);
    ba0 = *(const u16x8*)(Bp);
    ba1 = *(const u16x8*)(Bp + 8);
    ab0 = *(const u16x8*)(Ap + 32);
    ab1 = *(const u16x8*)(Ap + 40);
    bb0 = *(const u16x8*)(Bp + 32);
    bb1 = *(const u16x8*)(Bp + 40);

    for (int k0 = 0; k0 < K; k0 += 64) {
        // ---- step A: tile k0 ----
        if (k0) __syncthreads();
        *(u16x8*)(AsW)     = aa0;
        *(u16x8*)(AsW + 8) = aa1;
        *(u16x8*)(BsW)     = ba0;
        *(u16x8*)(BsW + 8) = ba1;
        __syncthreads();
        if (k0 + 64 < K) {
            aa0 = *(const u16x8*)(Ap + k0 + 64);
            aa1 = *(const u16x8*)(Ap + k0 + 72);
            ba0 = *(const u16x8*)(Bp + k0 + 64);
            ba1 = *(const u16x8*)(Bp + k0 + 72);
        }
        {
            bf16x8 af[4], bfv[4];
#pragma unroll
            for (int mi = 0; mi < 4; ++mi)
                af[mi] = __builtin_bit_cast(bf16x8,
                    *(const u16x8*)(&As[(wm + 16 * mi + fr) * LDST + fk]));
#pragma unroll
            for (int ni = 0; ni < 4; ++ni)
                bfv[ni] = __builtin_bit_cast(bf16x8,
                    *(const u16x8*)(&Bs[(wn + 16 * ni + fr) * LDST + fk]));
#pragma unroll
            for (int mi = 0; mi < 4; ++mi)
#pragma unroll
                for (int ni = 0; ni < 4; ++ni)
                    acc[mi][ni] = __builtin_amdgcn_mfma_f32_16x16x32_bf16(
                        af[mi], bfv[ni], acc[mi][ni], 0, 0, 0);
        }

        // ---- step B: tile k0+32 ----
        __syncthreads();
        *(u16x8*)(AsW)     = ab0;
        *(u16x8*)(AsW + 8) = ab1;
        *(u16x8*)(BsW)     = bb0;
        *(u16x8*)(BsW + 8) = bb1;
        __syncthreads();
        if (k0 + 96 < K) {
            ab0 = *(const u16x8*)(Ap + k0 + 96);
            ab1 = *(const u16x8*)(Ap + k0 + 104);
            bb0 = *(const u16x8*)(Bp + k0 + 96);
            bb1 = *(const u16x8*)(Bp + k0 + 104);
        }
        {
            bf16x8 af[4], bfv[4];
#pragma unroll
            for (int mi = 0; mi < 4; ++mi)
                af[mi] = __builtin_bit_cast(bf16x8,
                    *(const u16x8*)(&As[(wm + 16 * mi + fr) * LDST + fk]));
#pragma unroll
            for (int ni = 0; ni < 4; ++ni)
                bfv[ni] = __builtin_bit_cast(bf16x8,
                    *(const u16x8*)(&Bs[(wn + 16 * ni + fr) * LDST + fk]));
#pragma unroll
            for (int mi = 0; mi < 4; ++mi)
#pragma unroll
                for (int ni = 0; ni < 4; ++ni)
                    acc[mi][ni] = __builtin_amdgcn_mfma_f32_16x16x32_bf16(
                        af[mi], bfv[ni], acc[mi][ni], 0, 0, 0);
        }
    }

    // Epilogue (validated D layout: col = lane&15, row = (lane>>4)*4 + reg)
    const int orow0 = row0 + wm + (lane >> 4) * 4;
    const int ocol0 = col0 + wn + fr;
#pragma unroll
    for (int mi = 0; mi < 4; ++mi) {
#pragma unroll
        for (int ni = 0; ni < 4; ++ni) {
            const int col = ocol0 + ni * 16;
            const float bv = bias ? bias[col] : 0.0f;
#pragma unroll
            for (int r = 0; r < 4; ++r) {
                const int row = orow0 + mi * 16 + r;
                float v = acc[mi][ni][r] + bv;
                if (do_gelu) v = 0.5f * v * (1.0f + erff(v * 0.70710678118654752f));
                Cbf[(size_t)row * ldcbf + cboff + col] = f2bf(v);
            }
        }
    }
}

__global__ __launch_bounds__(256) void gemm128(
    const u16* __restrict__ A, const u16* __restrict__ Bt, int K,
    const float* __restrict__ bias, int do_gelu,
    u16* __restrict__ Cbf, int ldcbf)
{
    __shared__ u16 As[128 * LDST];
    __shared__ u16 Bs[128 * LDST];
    gemm128_core(A, Bt, K, bias, do_gelu, Cbf, ldcbf, 0,
                 blockIdx.y * 128, blockIdx.x * 128, As, Bs);
}

// cross-attn Q/K/V batched: z selects (A,B); output col offset z*768 in QKV.
__global__ __launch_bounds__(256) void gemm128_qkv3(
    const u16* __restrict__ A0, const u16* __restrict__ A1, const u16* __restrict__ A2,
    const u16* __restrict__ B0, const u16* __restrict__ B1, const u16* __restrict__ B2,
    u16* __restrict__ Cbf, int ldcbf)
{
    __shared__ u16 As[128 * LDST];
    __shared__ u16 Bs[128 * LDST];
    const int z = blockIdx.z;
    const u16* A = (z == 0) ? A0 : (z == 1) ? A1 : A2;
    const u16* B = (z == 0) ? B0 : (z == 1) ? B1 : B2;
    gemm128_core(A, B, DD, nullptr, 0, Cbf, ldcbf, z * DD,
                 blockIdx.y * 128, blockIdx.x * 128, As, Bs);
}

// ---------------------------------------------------------------------------
// 64x128-tile GEMM (skinny launches: Wo x2, MLP2 split-K). Depth-2 unroll.
// ---------------------------------------------------------------------------
static __device__ __forceinline__ void gemm64_core(
    const u16* __restrict__ A, const u16* __restrict__ Bt,
    int N, int Kstride, int Klen,
    const float* __restrict__ bias,
    const float* __restrict__ residf, const u16* __restrict__ residb,
    float* __restrict__ C, u16* __restrict__ Cbf, int ldcbf, int cboff,
    int do_gelu, int row0, int col0, u16* As, u16* Bs)
{
    const int tid  = threadIdx.x;
    const int lane = tid & 63;
    const int w    = tid >> 6;
    const int wm = (w >> 1) * 32;
    const int wn = (w & 1) * 64;

    const int arow = tid >> 2;
    const int akc  = (tid & 3) * 8;
    const int brow = tid >> 1;
    const int bkc  = (tid & 1) * 16;

    const u16* Ap = A  + (size_t)(row0 + arow) * Kstride + akc;
    const u16* Bp = Bt + (size_t)(col0 + brow) * Kstride + bkc;
    u16* AsW = &As[arow * LDST + akc];
    u16* BsW = &Bs[brow * LDST + bkc];

    const int fr = lane & 15;
    const int fk = (lane >> 4) * 8;

    f32x4 acc[2][4] = {};

    u16x8 a0, b00, b01, a1, b10, b11;
    a0  = *(const u16x8*)(Ap);
    b00 = *(const u16x8*)(Bp);
    b01 = *(const u16x8*)(Bp + 8);
    a1  = *(const u16x8*)(Ap + 32);
    b10 = *(const u16x8*)(Bp + 32);
    b11 = *(const u16x8*)(Bp + 40);

    for (int k0 = 0; k0 < Klen; k0 += 64) {
        if (k0) __syncthreads();
        *(u16x8*)AsW       = a0;
        *(u16x8*)BsW       = b00;
        *(u16x8*)(BsW + 8) = b01;
        __syncthreads();
        if (k0 + 64 < Klen) {
            a0  = *(const u16x8*)(Ap + k0 + 64);
            b00 = *(const u16x8*)(Bp + k0 + 64);
            b01 = *(const u16x8*)(Bp + k0 + 72);
        }
        {
            bf16x8 af[2], bfv[4];
#pragma unroll
            for (int mi = 0; mi < 2; ++mi)
                af[mi] = __builtin_bit_cast(bf16x8,
                    *(const u16x8*)(&As[(wm + 16 * mi + fr) * LDST + fk]));
#pragma unroll
            for (int ni = 0; ni < 4; ++ni)
                bfv[ni] = __builtin_bit_cast(bf16x8,
                    *(const u16x8*)(&Bs[(wn + 16 * ni + fr) * LDST + fk]));
#pragma unroll
            for (int mi = 0; mi < 2; ++mi)
#pragma unroll
                for (int ni = 0; ni < 4; ++ni)
                    acc[mi][ni] = __builtin_amdgcn_mfma_f32_16x16x32_bf16(
                        af[mi], bfv[ni], acc[mi][ni], 0, 0, 0);
        }

        __syncthreads();
        *(u16x8*)AsW       = a1;
        *(u16x8*)BsW       = b10;
        *(u16x8*)(BsW + 8) = b11;
        __syncthreads();
        if (k0 + 96 < Klen) {
            a1  = *(const u16x8*)(Ap + k0 + 96);
            b10 = *(const u16x8*)(Bp + k0 + 96);
            b11 = *(const u16x8*)(Bp + k0 + 104);
        }
        {
            bf16x8 af[2], bfv[4];
#pragma unroll
            for (int mi = 0; mi < 2; ++mi)
                af[mi] = __builtin_bit_cast(bf16x8,
                    *(const u16x8*)(&As[(wm + 16 * mi + fr) * LDST + fk]));
#pragma unroll
            for (int ni = 0; ni < 4; ++ni)
                bfv[ni] = __builtin_bit_cast(bf16x8,
                    *(const u16x8*)(&Bs[(wn + 16 * ni + fr) * LDST + fk]));
#pragma unroll
            for (int mi = 0; mi < 2; ++mi)
#pragma unroll
                for (int ni = 0; ni < 4; ++ni)
                    acc[mi][ni] = __builtin_amdgcn_mfma_f32_16x16x32_bf16(
                        af[mi], bfv[ni], acc[mi][ni], 0, 0, 0);
        }
    }

    const int orow0 = row0 + wm + (lane >> 4) * 4;
    const int ocol0 = col0 + wn + fr;
#pragma unroll
    for (int mi = 0; mi < 2; ++mi) {
#pragma unroll
        for (int ni = 0; ni < 4; ++ni) {
            const int col = ocol0 + ni * 16;
            const float bv = bias ? bias[col] : 0.0f;
#pragma unroll
            for (int r = 0; r < 4; ++r) {
                const int row = orow0 + mi * 16 + r;
                float v = acc[mi][ni][r] + bv;
                if (do_gelu) v = 0.5f * v * (1.0f + erff(v * 0.70710678118654752f));
                if (residf) v += residf[(size_t)row * N + col];
                if (residb) v += bf2f(residb[(size_t)row * N + col]);
                if (C)   C[(size_t)row * N + col] = v;
                if (Cbf) Cbf[(size_t)row * ldcbf + cboff + col] = f2bf(v);
            }
        }
    }
}

__global__ __launch_bounds__(256) void gemm64(
    const u16* __restrict__ A, const u16* __restrict__ Bt, int N, int K,
    const float* __restrict__ bias,
    const float* __restrict__ residf, const u16* __restrict__ residb,
    float* __restrict__ C, u16* __restrict__ Cbf, int ldcbf, int do_gelu)
{
    __shared__ u16 As[64 * LDST];
    __shared__ u16 Bs[128 * LDST];
    gemm64_core(A, Bt, N, K, K, bias, residf, residb, C, Cbf, ldcbf, 0, do_gelu,
                blockIdx.y * 64, blockIdx.x * 128, As, Bs);
}

__global__ __launch_bounds__(256) void gemm64_sk(
    const u16* __restrict__ A, const u16* __restrict__ Bt, int N, int Kstride,
    int Klen, float* __restrict__ Cpair)
{
    __shared__ u16 As[64 * LDST];
    __shared__ u16 Bs[128 * LDST];
    const int z = blockIdx.z;
    const int koff = z * Klen;
    gemm64_core(A + koff, Bt + koff, N, Kstride, Klen,
                nullptr, nullptr, nullptr,
                Cpair + (size_t)z * MROWS * N, nullptr, 0, 0, 0,
                blockIdx.y * 64, blockIdx.x * 128, As, Bs);
}

// ---------------------------------------------------------------------------
// Transpose + fp32->bf16
// ---------------------------------------------------------------------------
__global__ __launch_bounds__(256) void tcvt_kernel(
    const float* __restrict__ in, u16* __restrict__ out, int K, int N)
{
    __shared__ float t[32][33];
    const float* ib = in + (size_t)blockIdx.z * K * N;
    u16* ob = out + (size_t)blockIdx.z * K * N;
    const int n0 = blockIdx.x * 32, k0 = blockIdx.y * 32;
    const int tx = threadIdx.x & 31, ty = threadIdx.x >> 5;
#pragma unroll
    for (int j = 0; j < 4; ++j)
        t[ty + j * 8][tx] = ib[(size_t)(k0 + ty + j * 8) * N + n0 + tx];
    __syncthreads();
#pragma unroll
    for (int j = 0; j < 4; ++j)
        ob[(size_t)(n0 + ty + j * 8) * K + k0 + tx] = f2bf(t[tx][ty + j * 8]);
}

__global__ __launch_bounds__(256) void tcvt6_kernel(
    const float* __restrict__ w0, const float* __restrict__ w1,
    const float* __restrict__ w2, const float* __restrict__ w3,
    const float* __restrict__ w4, const float* __restrict__ w5,
    u16* __restrict__ Wm6)
{
    __shared__ float t[32][33];
    const int z = blockIdx.z;
    const int wi = z / 12, head = z % 12;
    const float* wsel = (wi == 0) ? w0 : (wi == 1) ? w1 : (wi == 2) ? w2 :
                        (wi == 3) ? w3 : (wi == 4) ? w4 : w5;
    const float* ib = wsel + (size_t)head * DD * DHD;
    u16* ob = Wm6 + (size_t)wi * DD * DD + (size_t)head * DHD * DD;
    const int n0 = blockIdx.x * 32, k0 = blockIdx.y * 32;
    const int tx = threadIdx.x & 31, ty = threadIdx.x >> 5;
#pragma unroll
    for (int j = 0; j < 4; ++j)
        t[ty + j * 8][tx] = ib[(size_t)(k0 + ty + j * 8) * DHD + n0 + tx];
    __syncthreads();
#pragma unroll
    for (int j = 0; j < 4; ++j)
        ob[(size_t)(n0 + ty + j * 8) * DD + k0 + tx] = f2bf(t[tx][ty + j * 8]);
}

__global__ __launch_bounds__(256) void cvt3_kernel(
    const float* __restrict__ s0, const float* __restrict__ s1,
    const float* __restrict__ s2,
    u16* __restrict__ d0, u16* __restrict__ d1, u16* __restrict__ d2, int n4)
{
    const int z = blockIdx.z;
    const float* s = (z == 0) ? s0 : (z == 1) ? s1 : s2;
    u16* d = (z == 0) ? d0 : (z == 1) ? d1 : d2;
    const int i = blockIdx.x * 256 + threadIdx.x;
    if (i < n4) {
        float4 v = ((const float4*)s)[i];
        ushort4 o;
        o.x = f2bf(v.x); o.y = f2bf(v.y); o.z = f2bf(v.z); o.w = f2bf(v.w);
        ((ushort4*)d)[i] = o;
    }
}

// ---------------------------------------------------------------------------
// MFMA flash attention, max-free exp2 softmax (validated R11).
// ---------------------------------------------------------------------------
#define AST 72
#define CSC 0.18033688011112042f   // 0.125 * log2(e)
__global__ __launch_bounds__(256) void attn_mfma_kernel(
    const u16* __restrict__ Q, const u16* __restrict__ K,
    const u16* __restrict__ V, int ldq, const int* __restrict__ kmask,
    u16* __restrict__ O, int causal)
{
    const int qt = causal ? ((int)gridDim.x - 1 - (int)blockIdx.x) : (int)blockIdx.x;
    const int bh = blockIdx.y;
    const int b  = bh / HH;
    const int h  = bh % HH;
    const int tid  = threadIdx.x;
    const int lane = tid & 63;
    const int w    = tid >> 6;
    const int lr = lane & 15;
    const int lg = lane >> 4;

    __shared__ u16 KPs[64 * AST];   // K tile; overwritten by P after QK^T
    __shared__ u16 Vt[64 * AST];

    const int row0 = qt * 64;
    const int q0w  = row0 + w * 16;

    bf16x8 qf[2];
    {
        const u16* qp = Q + (size_t)(b * SS + q0w + lr) * ldq + h * DHD + lg * 8;
        qf[0] = __builtin_bit_cast(bf16x8, *(const u16x8*)(qp));
        qf[1] = __builtin_bit_cast(bf16x8, *(const u16x8*)(qp + 32));
    }

    const int sr = tid >> 2;
    const int sc = (tid & 3) * 16;
    const int vkey = lane;
    const int vj = ((vkey & 15) << 2) | (vkey >> 4);   // permuted k-column
    const int dw = w * 16;

    f32x4 acc[4] = {};
    float lsum[4] = {0.0f, 0.0f, 0.0f, 0.0f};

    const int nkt = causal ? (qt + 1) : 16;

    u16x8 kr0, kr1, vr0, vr1;
    {
        const u16* kp = K + (size_t)(b * SS + sr) * ldq + h * DHD + sc;
        kr0 = *(const u16x8*)(kp);
        kr1 = *(const u16x8*)(kp + 8);
        const u16* vp = V + (size_t)(b * SS + vkey) * ldq + h * DHD + dw;
        vr0 = *(const u16x8*)(vp);
        vr1 = *(const u16x8*)(vp + 8);
    }

    for (int kt = 0; kt < nkt; ++kt) {
        const int kcol0 = kt * 64;
        if (kt) __syncthreads();        // all PV reads of KPs/Vt done

        *(u16x8*)(&KPs[sr * AST + sc])     = kr0;
        *(u16x8*)(&KPs[sr * AST + sc + 8]) = kr1;
#pragma unroll
        for (int j = 0; j < 8; ++j) Vt[(dw + j) * AST + vj] = vr0[j];
#pragma unroll
        for (int j = 0; j < 8; ++j) Vt[(dw + 8 + j) * AST + vj] = vr1[j];
        __syncthreads();

        if (kt + 1 < nkt) {
            const int kn = kcol0 + 64;
            const u16* kp = K + (size_t)(b * SS + kn + sr) * ldq + h * DHD + sc;
            kr0 = *(const u16x8*)(kp);
            kr1 = *(const u16x8*)(kp + 8);
            const u16* vp = V + (size_t)(b * SS + kn + vkey) * ldq + h * DHD + dw;
            vr0 = *(const u16x8*)(vp);
            vr1 = *(const u16x8*)(vp + 8);
        }

        // QK^T (consumes K tile)
        f32x4 s[4] = {};
#pragma unroll
        for (int fi = 0; fi < 4; ++fi) {
            bf16x8 kf0 = __builtin_bit_cast(bf16x8, *(const u16x8*)(&KPs[(fi * 16 + lr) * AST + lg * 8]));
            bf16x8 kf1 = __builtin_bit_cast(bf16x8, *(const u16x8*)(&KPs[(fi * 16 + lr) * AST + 32 + lg * 8]));
            s[fi] = __builtin_amdgcn_mfma_f32_16x16x32_bf16(qf[0], kf0, s[fi], 0, 0, 0);
            s[fi] = __builtin_amdgcn_mfma_f32_16x16x32_bf16(qf[1], kf1, s[fi], 0, 0, 0);
        }
        __syncthreads();   // K tile fully consumed; safe to overwrite with P

        float biasf[4];
#pragma unroll
        for (int fi = 0; fi < 4; ++fi)
            biasf[fi] = kmask[b * SS + kcol0 + fi * 16 + lr] ? 0.0f : -INFINITY;
        const bool diag = (causal != 0) && (kt == qt);

#pragma unroll
        for (int r = 0; r < 4; ++r) {
            const int qrow = q0w + lg * 4 + r;
            u16x4 pk;
            float rs = 0.0f;
#pragma unroll
            for (int fi = 0; fi < 4; ++fi) {
                float v = fmaf(s[fi][r], CSC, biasf[fi]);
                if (diag) {
                    const int key = kcol0 + fi * 16 + lr;
                    v = (key <= qrow) ? v : -INFINITY;
                }
                const float pv = exp2f(v);   // 0 for masked
                pk[fi] = f2bf(pv);
                rs += pv;
            }
            lsum[r] += rs;
            *(u16x4*)(&KPs[(w * 16 + lg * 4 + r) * AST + lr * 4]) = pk;
        }

        // PV: A = own strip of KPs (P), B = Vt; both k-permuted identically
#pragma unroll
        for (int kk = 0; kk < 2; ++kk) {
            bf16x8 pf = __builtin_bit_cast(bf16x8, *(const u16x8*)(&KPs[(w * 16 + lr) * AST + kk * 32 + lg * 8]));
#pragma unroll
            for (int di = 0; di < 4; ++di) {
                bf16x8 vf = __builtin_bit_cast(bf16x8, *(const u16x8*)(&Vt[(di * 16 + lr) * AST + kk * 32 + lg * 8]));
                acc[di] = __builtin_amdgcn_mfma_f32_16x16x32_bf16(pf, vf, acc[di], 0, 0, 0);
            }
        }
    }

    // one l-reduction for the whole kernel
#pragma unroll
    for (int r = 0; r < 4; ++r) {
        float l = lsum[r];
        l += __shfl_xor(l, 1);
        l += __shfl_xor(l, 2);
        l += __shfl_xor(l, 4);
        l += __shfl_xor(l, 8);
        const float inv = (l > 0.0f) ? (1.0f / l) : 0.0f;
        const size_t orow = (size_t)(b * SS + q0w + lg * 4 + r) * DD + h * DHD;
#pragma unroll
        for (int di = 0; di < 4; ++di)
            O[orow + di * 16 + lr] = f2bf(acc[di][r] * inv);
    }
}

// ---------------------------------------------------------------------------
// LayerNorm over last dim (768); nullable fp32 out / bf16 out.
// ---------------------------------------------------------------------------
__global__ __launch_bounds__(256) void ln_kernel(
    const float* __restrict__ X, const float* __restrict__ gma,
    const float* __restrict__ bta, float* __restrict__ Y, u16* __restrict__ Ybf)
{
    const int row = blockIdx.x;
    const int tid = threadIdx.x;
    const float* x = X + (size_t)row * DD;

    const float v0 = x[tid], v1 = x[tid + 256], v2 = x[tid + 512];

    __shared__ float sd[256];
    sd[tid] = v0 + v1 + v2;
    __syncthreads();
    for (int off = 128; off > 0; off >>= 1) {
        if (tid < off) sd[tid] += sd[tid + off];
        __syncthreads();
    }
    const float mean = sd[0] * (1.0f / 768.0f);
    __syncthreads();

    const float q0 = v0 - mean, q1 = v1 - mean, q2 = v2 - mean;
    sd[tid] = q0 * q0 + q1 * q1 + q2 * q2;
    __syncthreads();
    for (int off = 128; off > 0; off >>= 1) {
        if (tid < off) sd[tid] += sd[tid + off];
        __syncthreads();
    }
    const float var = sd[0] * (1.0f / 768.0f);
    const float inv = rsqrtf(var + 1e-5f);

    const float y0 = q0 * inv * gma[tid]       + bta[tid];
    const float y1 = q1 * inv * gma[tid + 256] + bta[tid + 256];
    const float y2 = q2 * inv * gma[tid + 512] + bta[tid + 512];
    if (Y) {
        float* y = Y + (size_t)row * DD;
        y[tid] = y0; y[tid + 256] = y1; y[tid + 512] = y2;
    }
    if (Ybf) {
        u16* yb = Ybf + (size_t)row * DD;
        yb[tid] = f2bf(y0); yb[tid + 256] = f2bf(y1); yb[tid + 512] = f2bf(y2);
    }
}

// ---------------------------------------------------------------------------
// LayerNorm over (C0 + C1 + bias + resid_bf16): split-K reduce fused in.
// ---------------------------------------------------------------------------
__global__ __launch_bounds__(256) void ln_red_kernel(
    const float* __restrict__ C0, const float* __restrict__ C1,
    const float* __restrict__ bias, const u16* __restrict__ resid,
    const float* __restrict__ gma, const float* __restrict__ bta,
    float* __restrict__ Y)
{
    const int row = blockIdx.x;
    const int tid = threadIdx.x;
    const size_t base = (size_t)row * DD;

    float v[3];
#pragma unroll
    for (int j = 0; j < 3; ++j) {
        const int i = tid + j * 256;
        v[j] = C0[base + i] + C1[base + i] + bias[i] + bf2f(resid[base + i]);
    }

    __shared__ float sd[256];
    sd[tid] = v[0] + v[1] + v[2];
    __syncthreads();
    for (int off = 128; off > 0; off >>= 1) {
        if (tid < off) sd[tid] += sd[tid + off];
        __syncthreads();
    }
    const float mean = sd[0] * (1.0f / 768.0f);
    __syncthreads();

    float q[3];
#pragma unroll
    for (int j = 0; j < 3; ++j) q[j] = v[j] - mean;
    sd[tid] = q[0] * q[0] + q[1] * q[1] + q[2] * q[2];
    __syncthreads();
    for (int off = 128; off > 0; off >>= 1) {
        if (tid < off) sd[tid] += sd[tid + off];
        __syncthreads();
    }
    const float var = sd[0] * (1.0f / 768.0f);
    const float inv = rsqrtf(var + 1e-5f);

    float* y = Y + base;
#pragma unroll
    for (int j = 0; j < 3; ++j) {
        const int i = tid + j * 256;
        y[i] = q[j] * inv * gma[i] + bta[i];
    }
}

// ---------------------------------------------------------------------------
extern "C" void kernel_launch(void* const* d_in, const int* in_sizes, int n_in,
                              void* d_out, int out_size, void* d_ws, size_t ws_size,
                              hipStream_t stream)
{
    (void)in_sizes; (void)n_in; (void)out_size; (void)ws_size;

    const float* key_enc   = (const float*)d_in[0];
    const float* value_enc = (const float*)d_in[1];
    const float* x         = (const float*)d_in[2];
    const int*   src_mask  = (const int*)d_in[3];
    const int*   tgt_mask  = (const int*)d_in[4];
    const float* Wq_m = (const float*)d_in[5];
    const float* Wk_m = (const float*)d_in[6];
    const float* Wv_m = (const float*)d_in[7];
    const float* Wo_m = (const float*)d_in[8];
    const float* Wq_c = (const float*)d_in[9];
    const float* Wk_c = (const float*)d_in[10];
    const float* Wv_c = (const float*)d_in[11];
    const float* Wo_c = (const float*)d_in[12];
    const float* ln1_g = (const float*)d_in[13];
    const float* ln1_b = (const float*)d_in[14];
    const float* ln2_g = (const float*)d_in[15];
    const float* ln2_b = (const float*)d_in[16];
    const float* ln3_g = (const float*)d_in[17];
    const float* ln3_b = (const float*)d_in[18];
    const float* W1 = (const float*)d_in[19];
    const float* b1 = (const float*)d_in[20];
    const float* W2 = (const float*)d_in[21];
    const float* b2 = (const float*)d_in[22];

    float* out = (float*)d_out;

    // workspace layout
    const size_t ACT = (size_t)MROWS * DD;
    const size_t WP  = (size_t)DD * DD;
    char* p = (char*)d_ws;
    u16* QKV  = (u16*)p;   p += 3 * ACT * 2;
    u16* BFx  = (u16*)p;   p += ACT * 2;
    u16* BFK  = (u16*)p;   p += ACT * 2;
    u16* BFV  = (u16*)p;   p += ACT * 2;
    u16* BF1a = (u16*)p;   p += ACT * 2;
    u16* BF1h = (u16*)p;   p += ACT * 2;
    float* T2 = (float*)p; p += ACT * 4;   // pre-LN fp32 / split-K partial 0
    float* T2b = (float*)p; p += ACT * 4;  // split-K partial 1
    u16* Wm6  = (u16*)p;   p += 6 * WP * 2;
    u16* Wom_t = (u16*)p;  p += WP * 2;
    u16* Woc_t = (u16*)p;  p += WP * 2;
    u16* W1t  = (u16*)p;   p += (size_t)DD * FF * 2;
    u16* W2t  = (u16*)p;   p += (size_t)DD * FF * 2;
    u16* MID  = QKV;   // [4096][3072] bf16 aliases QKV+BFx (dead by MLP)

    const dim3 blk(256);
    const int nc4 = (int)(ACT / 4);

    cvt3_kernel<<<dim3(nc4 / 256, 1, 3), blk, 0, stream>>>(
        x, key_enc, value_enc, BFx, BFK, BFV, nc4);
    tcvt6_kernel<<<dim3(2, 24, 72), blk, 0, stream>>>(
        Wq_m, Wk_m, Wv_m, Wq_c, Wk_c, Wv_c, Wm6);
    tcvt_kernel<<<dim3(24, 24, 1), blk, 0, stream>>>(Wo_m, Wom_t, DD, DD);
    tcvt_kernel<<<dim3(24, 24, 1), blk, 0, stream>>>(Wo_c, Woc_t, DD, DD);
    tcvt_kernel<<<dim3(96, 24, 1), blk, 0, stream>>>(W1, W1t, DD, FF);
    tcvt_kernel<<<dim3(24, 96, 1), blk, 0, stream>>>(W2, W2t, FF, DD);

    const dim3 gQKV(18, 32);      // 128x128: N=2304, 576 blocks
    const dim3 gP(6, 64);         // 64x128 skinny
    const dim3 gP3(6, 32, 3);     // 128x128 cross projections, 576 blocks
    const dim3 gM1(24, 32);       // 128x128: N=3072, 768 blocks
    const dim3 gM2(6, 64, 2);     // MLP2 split-K
    const dim3 gAttn(16, BB * HH);

    // Self-attention
    gemm128<<<gQKV, blk, 0, stream>>>(BFx, Wm6, DD, nullptr, 0, QKV, 3 * DD);
    attn_mfma_kernel<<<gAttn, blk, 0, stream>>>(QKV, QKV + DD, QKV + 2 * DD, 3 * DD,
                                                tgt_mask, BF1a, 1);
    gemm64<<<gP, blk, 0, stream>>>(BF1a, Wom_t, DD, DD,
                                   nullptr, x, nullptr,
                                   T2, nullptr, DD, 0);
    ln_kernel<<<MROWS, blk, 0, stream>>>(T2, ln1_g, ln1_b, nullptr, BF1h);

    // Cross-attention
    gemm128_qkv3<<<gP3, blk, 0, stream>>>(BF1h, BFK, BFV,
                                          Wm6 + 3 * WP, Wm6 + 4 * WP, Wm6 + 5 * WP,
                                          QKV, 3 * DD);
    attn_mfma_kernel<<<gAttn, blk, 0, stream>>>(QKV, QKV + DD, QKV + 2 * DD, 3 * DD,
                                                src_mask, BF1a, 0);
    gemm64<<<gP, blk, 0, stream>>>(BF1a, Woc_t, DD, DD,
                                   nullptr, nullptr, BF1h,
                                   T2, nullptr, DD, 0);
    ln_kernel<<<MROWS, blk, 0, stream>>>(T2, ln2_g, ln2_b, nullptr, BF1h);

    // MLP
    gemm128<<<gM1, blk, 0, stream>>>(BF1h, W1t, DD, b1, 1, MID, FF);
    gemm64_sk<<<gM2, blk, 0, stream>>>(MID, W2t, DD, FF, FF / 2, T2);
    ln_red_kernel<<<MROWS, blk, 0, stream>>>(T2, T2b, b2, BF1h,
                                             ln3_g, ln3_b, out);
}